// Round 1
// baseline (42.469 us; speedup 1.0000x reference)
//
#include <hip/hip_runtime.h>

#define NUF 100000
#define NIF 100000
#define DIM 64
#define LNZ 32
#define NB 16384
#define NI 16384
#define OUTW 66   // D + 2

// One wave (64 lanes) per output row. Lane = embedding dim.
// Rows [0, NB) are users, rows [NB, NB+NI) are items.
__global__ __launch_bounds__(256) void ensfm_kernel(
    const float* __restrict__ ue_emb,   // [NUF, 64]
    const float* __restrict__ ie_emb,   // [NIF, 64]
    const float* __restrict__ w_user,   // [NUF]
    const float* __restrict__ w_item,   // [NIF]
    const float* __restrict__ gbias,    // [1]
    const float* __restrict__ h1,       // [64]
    const float* __restrict__ h2,       // [64]
    const int*   __restrict__ u_idx,    // [NB, 32]
    const int*   __restrict__ i_idx,    // [NI, 32]
    float* __restrict__ out)            // P [NB,66] | Q [NI,66] | h2 [64]
{
    const int lane = threadIdx.x & 63;
    const int wib  = threadIdx.x >> 6;              // wave id in block (0..3)
    const int row  = blockIdx.x * 4 + wib;          // 0..32767

    // h2 passthrough (block 0 only)
    if (blockIdx.x == 0 && threadIdx.x < DIM) {
        out[(size_t)(NB + NI) * OUTW + threadIdx.x] = h2[threadIdx.x];
    }
    if (row >= NB + NI) return;

    const bool is_user = (row < NB);
    const int  r       = is_user ? row : (row - NB);
    const float* emb   = is_user ? ue_emb : ie_emb;
    const float* wtab  = is_user ? w_user : w_item;
    const int*   idxp  = is_user ? u_idx  : i_idx;

    // lanes 0..31: load this row's 32 indices + their w values (coalesced)
    int   myidx = 0;
    float wval  = 0.0f;
    if (lane < LNZ) {
        myidx = idxp[(size_t)r * LNZ + lane];
        wval  = wtab[myidx];
    }

    // w-sum: lanes >=32 hold 0, so a full 64-lane butterfly gives the sum of 32
    float wsum = wval;
    #pragma unroll
    for (int m = 1; m < 64; m <<= 1) wsum += __shfl_xor(wsum, m, 64);

    // gather-accumulate: su = sum_l e, ss = sum_l e^2
    float su = 0.0f, ss = 0.0f;
    #pragma unroll 8
    for (int l = 0; l < LNZ; ++l) {
        int idx = __shfl(myidx, l, 64);             // broadcast from lane l
        float e = emb[(size_t)idx * DIM + lane];    // coalesced 256B/wave
        su += e;
        ss = fmaf(e, e, ss);
    }

    // bi = 0.5*(su^2 - ss); scal = dot(bi, h1) + wsum (+ bias for users)
    float bi  = 0.5f * (su * su - ss);
    float dot = bi * h1[lane];
    #pragma unroll
    for (int m = 1; m < 64; m <<= 1) dot += __shfl_xor(dot, m, 64);

    float scal = dot + wsum + (is_user ? gbias[0] : 0.0f);

    float* orow = out + (size_t)row * OUTW;
    orow[lane] = su;
    if (lane == 0) {
        if (is_user) { orow[DIM] = scal; orow[DIM + 1] = 1.0f; }
        else         { orow[DIM] = 1.0f; orow[DIM + 1] = scal; }
    }
}

extern "C" void kernel_launch(void* const* d_in, const int* in_sizes, int n_in,
                              void* d_out, int out_size, void* d_ws, size_t ws_size,
                              hipStream_t stream) {
    const float* ue_emb = (const float*)d_in[0];
    const float* ie_emb = (const float*)d_in[1];
    const float* w_user = (const float*)d_in[2];
    const float* w_item = (const float*)d_in[3];
    const float* gbias  = (const float*)d_in[4];
    const float* h1     = (const float*)d_in[5];
    const float* h2     = (const float*)d_in[6];
    const int*   u_idx  = (const int*)d_in[7];
    const int*   i_idx  = (const int*)d_in[8];
    float* out = (float*)d_out;

    const int total_rows = NB + NI;                 // 32768
    const int blocks = total_rows / 4;              // 8192 blocks x 256 threads
    ensfm_kernel<<<blocks, 256, 0, stream>>>(
        ue_emb, ie_emb, w_user, w_item, gbias, h1, h2, u_idx, i_idx, out);
}